// Round 1
// baseline (2364.219 us; speedup 1.0000x reference)
//
#include <hip/hip_runtime.h>
#include <hip/hip_bf16.h>
#include <math.h>

#define NWIN 5376   // 2 * 24 * 16 * 7 windows
#define NTOK 24
#define DIM 192
#define HEADS 6
#define HDIM 32
#define HID 768

// LDS region plan (single 59904 B arena, manually aliased):
//  A [    0 .. 18432) : sH f32 24x192  -> sO f32 24x192 -> sHid bf16 24x384
//  B [18432 .. 46080) : sQKV bf16 24x576 -> sXw2 f32 24x192
//  C [46080 .. 59904) : sS f32 6x24x24 -> sH2 bf16 24x192
__global__ __launch_bounds__(256, 2)
void pangu_block_kernel(
    const float* __restrict__ x,
    const float* __restrict__ ln1_g, const float* __restrict__ ln1_b,
    const float* __restrict__ qkv_w, const float* __restrict__ qkv_b,
    const float* __restrict__ bias_table,
    const float* __restrict__ proj_w, const float* __restrict__ proj_b,
    const float* __restrict__ ln2_g, const float* __restrict__ ln2_b,
    const float* __restrict__ mlp_w1, const float* __restrict__ mlp_b1,
    const float* __restrict__ mlp_w2, const float* __restrict__ mlp_b2,
    const int* __restrict__ rel_index,
    float* __restrict__ out)
{
    __shared__ __align__(16) char smem[59904];
    __shared__ int sRowOff[NTOK];
    __shared__ float sMu[NTOK], sRs[NTOK];

    float*          sH   = (float*)smem;
    __hip_bfloat16* sQKV = (__hip_bfloat16*)(smem + 18432);
    float*          sS   = (float*)(smem + 46080);
    float*          sO   = (float*)smem;                     // alias A
    float*          sXw2 = (float*)(smem + 18432);           // alias B
    __hip_bfloat16* sH2  = (__hip_bfloat16*)(smem + 46080);  // alias C
    __hip_bfloat16* sHid = (__hip_bfloat16*)smem;            // alias A

    const int t = threadIdx.x;
    const int w = blockIdx.x;

    // window -> 24 global row offsets (element offsets into x / out)
    if (t < NTOK) {
        int idx = w;
        int id_ = idx % 7;  idx /= 7;
        int iw_ = idx % 16; idx /= 16;
        int ih_ = idx % 24; idx /= 24;
        int b   = idx;
        int i = t / 12, j = (t % 12) / 2, k = t % 2;
        int hh = ih_ * 2 + i, ww = iw_ * 6 + j, dd = id_ * 2 + k;
        sRowOff[t] = (((b * 48 + hh) * 96 + ww) * 14 + dd) * DIM;
    }
    __syncthreads();

    // ---- Phase 0: load x window -> sH (fp32, float4 coalesced) ----
    for (int q = t; q < NTOK * (DIM / 4); q += 256) {
        int r = q / (DIM / 4), c4 = q % (DIM / 4);
        *(float4*)(sH + r * DIM + c4 * 4) = *(const float4*)(x + sRowOff[r] + c4 * 4);
    }
    __syncthreads();

    // ---- Phase 1: LN1 stats (8 lanes per row) ----
    if (t < NTOK * 8) {
        int r = t >> 3, l = t & 7;
        float s = 0.f, s2 = 0.f;
        for (int c = l; c < DIM; c += 8) { float v = sH[r * DIM + c]; s += v; s2 += v * v; }
        s += __shfl_xor(s, 1); s2 += __shfl_xor(s2, 1);
        s += __shfl_xor(s, 2); s2 += __shfl_xor(s2, 2);
        s += __shfl_xor(s, 4); s2 += __shfl_xor(s2, 4);
        if (l == 0) {
            float mu = s * (1.f / DIM);
            float var = s2 * (1.f / DIM) - mu * mu;
            sMu[r] = mu;
            sRs[r] = rsqrtf(var + 1e-5f);
        }
    }
    __syncthreads();
    // ---- Phase 2: LN1 normalize in place ----
    for (int q = t; q < NTOK * DIM; q += 256) {
        int r = q / DIM, c = q % DIM;
        sH[q] = (sH[q] - sMu[r]) * sRs[r] * ln1_g[c] + ln1_b[c];
    }
    __syncthreads();

    const int tx = t & 63, ty = t >> 6;

    // ---- Phase 3: QKV GEMM  M=24(4x6) N=576(64x9) K=192 ----
    {
        float acc[6][9];
        #pragma unroll
        for (int jj = 0; jj < 9; ++jj) {
            float bb = qkv_b[tx + 64 * jj];
            #pragma unroll
            for (int ii = 0; ii < 6; ++ii) acc[ii][jj] = bb;
        }
        const float* Hb = sH + ty * 6 * DIM;
        for (int k = 0; k < DIM; ++k) {
            float a[6];
            #pragma unroll
            for (int ii = 0; ii < 6; ++ii) a[ii] = Hb[ii * DIM + k];
            const float* Wk = qkv_w + k * 576 + tx;
            #pragma unroll
            for (int jj = 0; jj < 9; ++jj) {
                float bw = Wk[64 * jj];
                #pragma unroll
                for (int ii = 0; ii < 6; ++ii) acc[ii][jj] += a[ii] * bw;
            }
        }
        #pragma unroll
        for (int ii = 0; ii < 6; ++ii)
            #pragma unroll
            for (int jj = 0; jj < 9; ++jj)
                sQKV[(ty * 6 + ii) * 576 + tx + 64 * jj] = __float2bfloat16(acc[ii][jj]);
    }
    __syncthreads();

    // ---- Phase 4a: S = scale * q.k^T + bias ----
    for (int o = t; o < HEADS * NTOK * NTOK; o += 256) {
        int h = o / (NTOK * NTOK), rem = o % (NTOK * NTOK);
        int n = rem / NTOK, m = rem % NTOK;
        const __hip_bfloat162* qp = (const __hip_bfloat162*)(sQKV + n * 576 + h * HDIM);
        const __hip_bfloat162* kp = (const __hip_bfloat162*)(sQKV + m * 576 + DIM + h * HDIM);
        float acc = 0.f;
        #pragma unroll
        for (int d2 = 0; d2 < HDIM / 2; ++d2) {
            float2 qf = __bfloat1622float2(qp[d2]);
            float2 kf = __bfloat1622float2(kp[d2]);
            acc += qf.x * kf.x;
            acc += qf.y * kf.y;
        }
        sS[o] = acc * 0.1767766952966369f
              + bias_table[rel_index[n * NTOK + m] * HEADS + h];
    }
    __syncthreads();
    // ---- Phase 4b: softmax over m (one thread per (h,n) row) ----
    if (t < HEADS * NTOK) {
        float* row = sS + t * NTOK;
        float mx = row[0];
        #pragma unroll
        for (int m = 1; m < NTOK; ++m) mx = fmaxf(mx, row[m]);
        float sum = 0.f;
        #pragma unroll
        for (int m = 0; m < NTOK; ++m) { float e = __expf(row[m] - mx); row[m] = e; sum += e; }
        float inv = 1.f / sum;
        #pragma unroll
        for (int m = 0; m < NTOK; ++m) row[m] *= inv;
    }
    __syncthreads();
    // ---- Phase 4c: O = P @ V -> sO (overwrites sH, dead) ----
    for (int o = t; o < NTOK * DIM; o += 256) {
        int n = o / DIM, c = o % DIM, h = c / HDIM;
        const float* Pr = sS + (h * NTOK + n) * NTOK;
        float acc = 0.f;
        #pragma unroll
        for (int m = 0; m < NTOK; ++m)
            acc += Pr[m] * __bfloat162float(sQKV[m * 576 + 2 * DIM + c]);
        sO[o] = acc;
    }
    __syncthreads();

    // ---- Phase 5: proj GEMM M=24 N=192(64x3) K=192, + residual -> sXw2 ----
    {
        float acc[6][3];
        #pragma unroll
        for (int jj = 0; jj < 3; ++jj) {
            float bb = proj_b[tx + 64 * jj];
            #pragma unroll
            for (int ii = 0; ii < 6; ++ii) acc[ii][jj] = bb;
        }
        const float* Ob = sO + ty * 6 * DIM;
        for (int k = 0; k < DIM; ++k) {
            float a[6];
            #pragma unroll
            for (int ii = 0; ii < 6; ++ii) a[ii] = Ob[ii * DIM + k];
            const float* Wk = proj_w + k * DIM + tx;
            #pragma unroll
            for (int jj = 0; jj < 3; ++jj) {
                float bw = Wk[64 * jj];
                #pragma unroll
                for (int ii = 0; ii < 6; ++ii) acc[ii][jj] += a[ii] * bw;
            }
        }
        // residual with re-read of x (L2-hot); sXw2 overwrites sQKV (dead)
        #pragma unroll
        for (int ii = 0; ii < 6; ++ii) {
            int r = ty * 6 + ii;
            #pragma unroll
            for (int jj = 0; jj < 3; ++jj) {
                int c = tx + 64 * jj;
                sXw2[r * DIM + c] = x[sRowOff[r] + c] + acc[ii][jj];
            }
        }
    }
    __syncthreads();

    // ---- Phase 6: LN2 -> sH2 (bf16, overwrites sS) ----
    if (t < NTOK * 8) {
        int r = t >> 3, l = t & 7;
        float s = 0.f, s2 = 0.f;
        for (int c = l; c < DIM; c += 8) { float v = sXw2[r * DIM + c]; s += v; s2 += v * v; }
        s += __shfl_xor(s, 1); s2 += __shfl_xor(s2, 1);
        s += __shfl_xor(s, 2); s2 += __shfl_xor(s2, 2);
        s += __shfl_xor(s, 4); s2 += __shfl_xor(s2, 4);
        if (l == 0) {
            float mu = s * (1.f / DIM);
            float var = s2 * (1.f / DIM) - mu * mu;
            sMu[r] = mu;
            sRs[r] = rsqrtf(var + 1e-5f);
        }
    }
    __syncthreads();
    for (int q = t; q < NTOK * DIM; q += 256) {
        int r = q / DIM, c = q % DIM;
        sH2[q] = __float2bfloat16((sXw2[q] - sMu[r]) * sRs[r] * ln2_g[c] + ln2_b[c]);
    }
    __syncthreads();

    // ---- Phase 7: MLP in two 384-wide chunks; acc2 carries MLP2 partials ----
    float acc2[6][3];
    #pragma unroll
    for (int jj = 0; jj < 3; ++jj) {
        float bb = mlp_b2[tx + 64 * jj];
        #pragma unroll
        for (int ii = 0; ii < 6; ++ii) acc2[ii][jj] = bb;
    }
    for (int ch = 0; ch < 2; ++ch) {
        float acc1[6][6];
        #pragma unroll
        for (int jj = 0; jj < 6; ++jj) {
            float bb = mlp_b1[ch * 384 + tx + 64 * jj];
            #pragma unroll
            for (int ii = 0; ii < 6; ++ii) acc1[ii][jj] = bb;
        }
        const __hip_bfloat16* H2b = sH2 + ty * 6 * DIM;
        for (int k = 0; k < DIM; ++k) {
            float a[6];
            #pragma unroll
            for (int ii = 0; ii < 6; ++ii) a[ii] = __bfloat162float(H2b[ii * DIM + k]);
            const float* Wk = mlp_w1 + k * HID + ch * 384 + tx;
            #pragma unroll
            for (int jj = 0; jj < 6; ++jj) {
                float bw = Wk[64 * jj];
                #pragma unroll
                for (int ii = 0; ii < 6; ++ii) acc1[ii][jj] += a[ii] * bw;
            }
        }
        __syncthreads();   // prev chunk's sHid readers done before overwrite
        #pragma unroll
        for (int ii = 0; ii < 6; ++ii) {
            int r = ty * 6 + ii;
            #pragma unroll
            for (int jj = 0; jj < 6; ++jj) {
                float v = acc1[ii][jj];
                float g = 0.5f * v * (1.f + erff(v * 0.70710678118654752f));
                sHid[r * 384 + tx + 64 * jj] = __float2bfloat16(g);
            }
        }
        __syncthreads();
        const __hip_bfloat16* Hb2 = sHid + ty * 6 * 384;
        for (int k = 0; k < 384; ++k) {
            float a[6];
            #pragma unroll
            for (int ii = 0; ii < 6; ++ii) a[ii] = __bfloat162float(Hb2[ii * 384 + k]);
            const float* Wk = mlp_w2 + (ch * 384 + k) * DIM + tx;
            #pragma unroll
            for (int jj = 0; jj < 3; ++jj) {
                float bw = Wk[64 * jj];
                #pragma unroll
                for (int ii = 0; ii < 6; ++ii) acc2[ii][jj] += a[ii] * bw;
            }
        }
    }

    // ---- Phase 8: out = xw2 + mlp ----
    #pragma unroll
    for (int ii = 0; ii < 6; ++ii) {
        int r = ty * 6 + ii;
        #pragma unroll
        for (int jj = 0; jj < 3; ++jj) {
            int c = tx + 64 * jj;
            out[sRowOff[r] + c] = sXw2[r * DIM + c] + acc2[ii][jj];
        }
    }
}

extern "C" void kernel_launch(void* const* d_in, const int* in_sizes, int n_in,
                              void* d_out, int out_size, void* d_ws, size_t ws_size,
                              hipStream_t stream) {
    const float* x          = (const float*)d_in[0];
    const float* ln1_g      = (const float*)d_in[1];
    const float* ln1_b      = (const float*)d_in[2];
    const float* qkv_w      = (const float*)d_in[3];
    const float* qkv_b      = (const float*)d_in[4];
    const float* bias_table = (const float*)d_in[5];
    const float* proj_w     = (const float*)d_in[6];
    const float* proj_b     = (const float*)d_in[7];
    const float* ln2_g      = (const float*)d_in[8];
    const float* ln2_b      = (const float*)d_in[9];
    const float* mlp_w1     = (const float*)d_in[10];
    const float* mlp_b1     = (const float*)d_in[11];
    const float* mlp_w2     = (const float*)d_in[12];
    const float* mlp_b2     = (const float*)d_in[13];
    const int*   rel_index  = (const int*)d_in[14];
    float* out = (float*)d_out;

    pangu_block_kernel<<<NWIN, 256, 0, stream>>>(
        x, ln1_g, ln1_b, qkv_w, qkv_b, bias_table, proj_w, proj_b,
        ln2_g, ln2_b, mlp_w1, mlp_b1, mlp_w2, mlp_b2, rel_index, out);
}

// Round 3
// 679.630 us; speedup vs baseline: 3.4787x; 3.4787x over previous
//
#include <hip/hip_runtime.h>
#include <hip/hip_bf16.h>
#include <math.h>

typedef __bf16 bf16_t;
typedef __bf16 bf16x8 __attribute__((ext_vector_type(8)));
typedef float  f32x4  __attribute__((ext_vector_type(4)));

#define NBLK 2688          // 5376 windows / 2 per block
// bf16 element offsets of pre-swizzled weights inside d_ws
#define WF_QKV  0
#define WF_PROJ 110592
#define WF_MLP1 147456
#define WF_MLP2 294912

// ---------------- weight pre-swizzle: W[K][N] f32 -> B-fragment bf16 ----------------
// frag(nt,kt): dst[((nt*Kt + kt)*64 + lane)*8 + j] = W[kt*32 + (lane>>4)*8 + j][nt*16 + (lane&15)]
__global__ void preproc_kernel(const float* __restrict__ W, int N, int Kt,
                               bf16_t* __restrict__ dst, int npairs) {
    int p = blockIdx.x * 256 + threadIdx.x;
    if (p >= npairs) return;
    int j    = (p & 3) * 2;
    int lane = (p >> 2) & 63;
    int kt   = (p >> 8) % Kt;
    int nt   = (p >> 8) / Kt;
    int k = kt * 32 + (lane >> 4) * 8 + j;
    int n = nt * 16 + (lane & 15);
    union { bf16_t h[2]; unsigned u; } pk;
    pk.h[0] = (bf16_t)W[k * N + n];
    pk.h[1] = (bf16_t)W[(k + 1) * N + n];
    *(unsigned*)(dst + p * 2) = pk.u;
}

// ---------------- main fused kernel ----------------
// LDS arena (80640 B). bf16 activation rows: 192 cols in 448-B rows (224 elems).
//  aA   [0,28672)      bf16 [64][224]  LN1 out / QKV A (pad rows 24..31,56..63 garbage)
//  xtmp [28672,65536)  f32  [48][192]  phase 0 only (aliases wavebufs)
//  wavebufs 28672+wv*8320: Q[24][40] K[24][40] Vt[32][40] P[24][40] bf16
//  aO   [0,21504)      bf16 [48][224]  attn out / proj A  (aliases aA; barrier after QKV MFMA)
//  aH2  [0,21504)      bf16 [48][224]  LN2 out / MLP1 A   (aliases aO, dead)
//  aHid [21504,43008)  bf16 [48][224]  gelu chunk / MLP2 A
//  xw2  [43008,80640)  f32  [48][196]  residual1 (written after proj sync)
__global__ __launch_bounds__(384, 3)
void pangu_main(const float* __restrict__ x,
                const float* __restrict__ ln1_g, const float* __restrict__ ln1_b,
                const float* __restrict__ qkv_b,
                const float* __restrict__ bias_table,
                const float* __restrict__ proj_b,
                const float* __restrict__ ln2_g, const float* __restrict__ ln2_b,
                const float* __restrict__ mlp_b1, const float* __restrict__ mlp_b2,
                const int* __restrict__ rel_index,
                const bf16_t* __restrict__ wf,
                float* __restrict__ out)
{
    __shared__ __align__(16) unsigned char arena[80640];
    __shared__ int   sRowOff[48];
    __shared__ float sMu[48], sRs[48];

    unsigned char* aAb   = arena;
    float*         xtmp  = (float*)(arena + 28672);
    unsigned char* aOb   = arena;                 // alias aA (post-QKV barrier)
    unsigned char* aH2b  = arena;                 // alias aO (dead)
    unsigned char* aHidb = arena + 21504;
    float*         xw2   = (float*)(arena + 43008);
    bf16_t* aA   = (bf16_t*)aAb;
    bf16_t* aO   = (bf16_t*)aOb;
    bf16_t* aH2  = (bf16_t*)aH2b;
    bf16_t* aHid = (bf16_t*)aHidb;

    const int t    = threadIdx.x;
    const int lane = t & 63;
    const int wv   = t >> 6;          // 0..5 (wave id == head id)
    const int quad = lane >> 4;
    const int l15  = lane & 15;
    const int q4   = quad * 4;

    // ---- row offsets of the 48 tokens (2 windows) ----
    if (t < 48) {
        int win = t / 24, tok = t % 24;
        int W = blockIdx.x * 2 + win;
        int id_ = W % 7;  int r1 = W / 7;
        int iw_ = r1 % 16; int r2 = r1 / 16;
        int ih_ = r2 % 24; int b  = r2 / 24;
        int i = tok / 12, j = (tok % 12) / 2, k = tok % 2;
        sRowOff[t] = (((b * 48 + ih_ * 2 + i) * 96 + iw_ * 6 + j) * 14 + id_ * 2 + k) * 192;
    }
    __syncthreads();

    // ---- phase 0: x -> xtmp (float4 coalesced) ----
    for (int q = t; q < 48 * 48; q += 384) {
        int r = q / 48, c4 = q % 48;
        *(float4*)(xtmp + r * 192 + c4 * 4) = *(const float4*)(x + sRowOff[r] + c4 * 4);
    }
    __syncthreads();

    // ---- LN1 stats: 8 lanes/row (384 = 48*8) ----
    {
        int r = t >> 3, l = t & 7;
        const float* row = xtmp + r * 192;
        float s = 0.f, s2 = 0.f;
        for (int c = l; c < 192; c += 8) { float v = row[c]; s += v; s2 += v * v; }
        s += __shfl_xor(s, 1); s2 += __shfl_xor(s2, 1);
        s += __shfl_xor(s, 2); s2 += __shfl_xor(s2, 2);
        s += __shfl_xor(s, 4); s2 += __shfl_xor(s2, 4);
        if (l == 0) {
            float mu = s * (1.f / 192.f);
            float var = s2 * (1.f / 192.f) - mu * mu;
            sMu[r] = mu; sRs[r] = rsqrtf(var + 1e-5f);
        }
    }
    __syncthreads();
    // ---- LN1 normalize -> aA (bf16 pairs, padded 64-row layout, 448-B rows) ----
    for (int p = t; p < 4608; p += 384) {
        int r48 = p / 96, c2 = p % 96, c = c2 * 2;
        int row = (r48 / 24) * 32 + (r48 % 24);
        float mu = sMu[r48], rs = sRs[r48];
        float v0 = (xtmp[r48 * 192 + c]     - mu) * rs * ln1_g[c]     + ln1_b[c];
        float v1 = (xtmp[r48 * 192 + c + 1] - mu) * rs * ln1_g[c + 1] + ln1_b[c + 1];
        union { bf16_t h[2]; unsigned u; } pk;
        pk.h[0] = (bf16_t)v0; pk.h[1] = (bf16_t)v1;
        *(unsigned*)(aAb + row * 448 + c2 * 4) = pk.u;
    }
    __syncthreads();

    // ================= QKV GEMM + attention =================
    {
        const int h = wv;
        unsigned char* wb = arena + 28672 + wv * 8320;
        bf16_t* Qb = (bf16_t*)wb;
        bf16_t* Kb = (bf16_t*)(wb + 1920);
        bf16_t* Vt = (bf16_t*)(wb + 3840);
        bf16_t* Pb = (bf16_t*)(wb + 6400);

        // QKV mini-GEMM: M tiles 0..3 (both windows), N = head's q/k/v (6 ntiles), K = 6 ktiles
        f32x4 acc[4][6];
        {
            float bq[6];
            const int ntg[6] = {2*h, 2*h+1, 12+2*h, 13+2*h, 24+2*h, 25+2*h};
            #pragma unroll
            for (int n = 0; n < 6; ++n) bq[n] = qkv_b[ntg[n] * 16 + l15];
            #pragma unroll
            for (int m = 0; m < 4; ++m)
                #pragma unroll
                for (int n = 0; n < 6; ++n)
                    acc[m][n] = (f32x4){bq[n], bq[n], bq[n], bq[n]};
            for (int kt = 0; kt < 6; ++kt) {
                bf16x8 af[4];
                #pragma unroll
                for (int m = 0; m < 4; ++m)
                    af[m] = *(const bf16x8*)(aAb + (l15 + m * 16) * 448 + kt * 64 + quad * 16);
                #pragma unroll
                for (int n = 0; n < 6; ++n) {
                    bf16x8 bfr = *(const bf16x8*)(wf + WF_QKV + ((ntg[n] * 6 + kt) * 64 + lane) * 8);
                    #pragma unroll
                    for (int m = 0; m < 4; ++m)
                        acc[m][n] = __builtin_amdgcn_mfma_f32_16x16x32_bf16(af[m], bfr, acc[m][n], 0, 0, 0);
                }
            }
        }
        __syncthreads();   // all waves done reading aA; aO (alias) may be written below

        // zero Vt pad tokens 24..31 (once; reused for both windows)
        {
            int c = lane >> 1, half = lane & 1;
            *(uint2*)((unsigned char*)Vt + c * 80 + 48 + half * 8) = make_uint2(0u, 0u);
        }

        const float scale = 0.1767766952966369f;  // 1/sqrt(32)
        #pragma unroll
        for (int win = 0; win < 2; ++win) {
            // scatter Q (scaled), K, V^T into wave-private bufs
            #pragma unroll
            for (int mt = 0; mt < 2; ++mt)
                #pragma unroll
                for (int i = 0; i < 4; ++i) {
                    int tok = mt * 16 + q4 + i;
                    if (tok < 24) {
                        #pragma unroll
                        for (int nt = 0; nt < 2; ++nt) {
                            int d = nt * 16 + l15;
                            Qb[tok * 40 + d]  = (bf16_t)(acc[2*win+mt][nt][i] * scale);
                            Kb[tok * 40 + d]  = (bf16_t)(acc[2*win+mt][2+nt][i]);
                            Vt[d * 40 + tok]  = (bf16_t)(acc[2*win+mt][4+nt][i]);
                        }
                    }
                }
            // S = Qs.K^T + bias  (bias gathered as C-init)
            f32x4 sacc[2][2];
            #pragma unroll
            for (int mt = 0; mt < 2; ++mt)
                #pragma unroll
                for (int nt = 0; nt < 2; ++nt)
                    #pragma unroll
                    for (int i = 0; i < 4; ++i) {
                        int n = mt * 16 + q4 + i; if (n > 23) n = 23;
                        int m = nt * 16 + l15;    if (m > 23) m = 23;
                        sacc[mt][nt][i] = bias_table[rel_index[n * 24 + m] * 6 + h];
                    }
            #pragma unroll
            for (int nt = 0; nt < 2; ++nt) {
                bf16x8 kf = *(const bf16x8*)((unsigned char*)Kb + (l15 + nt * 16) * 80 + quad * 16);
                #pragma unroll
                for (int mt = 0; mt < 2; ++mt) {
                    bf16x8 qf = *(const bf16x8*)((unsigned char*)Qb + (l15 + mt * 16) * 80 + quad * 16);
                    sacc[mt][nt] = __builtin_amdgcn_mfma_f32_16x16x32_bf16(qf, kf, sacc[mt][nt], 0, 0, 0);
                }
            }
            // in-register softmax over cols 0..23 (row lives in 16 lanes of one quad)
            #pragma unroll
            for (int mt = 0; mt < 2; ++mt)
                #pragma unroll
                for (int i = 0; i < 4; ++i) {
                    float s0 = sacc[mt][0][i];
                    float s1m = (l15 < 8) ? sacc[mt][1][i] : -1e30f;
                    float mx = fmaxf(s0, s1m);
                    mx = fmaxf(mx, __shfl_xor(mx, 1));
                    mx = fmaxf(mx, __shfl_xor(mx, 2));
                    mx = fmaxf(mx, __shfl_xor(mx, 4));
                    mx = fmaxf(mx, __shfl_xor(mx, 8));
                    float e0 = __expf(s0 - mx);
                    float e1 = (l15 < 8) ? __expf(sacc[mt][1][i] - mx) : 0.f;
                    float sum = e0 + e1;
                    sum += __shfl_xor(sum, 1);
                    sum += __shfl_xor(sum, 2);
                    sum += __shfl_xor(sum, 4);
                    sum += __shfl_xor(sum, 8);
                    float inv = 1.f / sum;
                    sacc[mt][0][i] = e0 * inv;
                    sacc[mt][1][i] = e1 * inv;   // 0 for cols 24..31
                }
            // P -> LDS (A-operand layout; cols 24..31 zeros)
            #pragma unroll
            for (int mt = 0; mt < 2; ++mt)
                #pragma unroll
                for (int i = 0; i < 4; ++i) {
                    int r = mt * 16 + q4 + i;
                    if (r < 24) {
                        Pb[r * 40 + l15]      = (bf16_t)sacc[mt][0][i];
                        Pb[r * 40 + 16 + l15] = (bf16_t)sacc[mt][1][i];
                    }
                }
            // O = P.V
            f32x4 oacc[2][2];
            #pragma unroll
            for (int mt = 0; mt < 2; ++mt)
                #pragma unroll
                for (int nt = 0; nt < 2; ++nt)
                    oacc[mt][nt] = (f32x4){0.f, 0.f, 0.f, 0.f};
            #pragma unroll
            for (int nt = 0; nt < 2; ++nt) {
                bf16x8 vf = *(const bf16x8*)((unsigned char*)Vt + (l15 + nt * 16) * 80 + quad * 16);
                #pragma unroll
                for (int mt = 0; mt < 2; ++mt) {
                    bf16x8 pf = *(const bf16x8*)((unsigned char*)Pb + (l15 + mt * 16) * 80 + quad * 16);
                    oacc[mt][nt] = __builtin_amdgcn_mfma_f32_16x16x32_bf16(pf, vf, oacc[mt][nt], 0, 0, 0);
                }
            }
            // O -> aO (48-row compact, proj A layout)
            #pragma unroll
            for (int mt = 0; mt < 2; ++mt)
                #pragma unroll
                for (int i = 0; i < 4; ++i) {
                    int tok = mt * 16 + q4 + i;
                    if (tok < 24) {
                        int r = win * 24 + tok;
                        #pragma unroll
                        for (int nt = 0; nt < 2; ++nt)
                            aO[r * 224 + h * 32 + nt * 16 + l15] = (bf16_t)oacc[mt][nt][i];
                    }
                }
        } // win
    }
    __syncthreads();

    // ================= proj GEMM (M=48, 2 ntiles/wave) + residual =================
    {
        f32x4 pacc[3][2];
        #pragma unroll
        for (int m = 0; m < 3; ++m)
            #pragma unroll
            for (int n = 0; n < 2; ++n) pacc[m][n] = (f32x4){0.f, 0.f, 0.f, 0.f};
        for (int kt = 0; kt < 6; ++kt) {
            bf16x8 af[3];
            #pragma unroll
            for (int m = 0; m < 3; ++m)
                af[m] = *(const bf16x8*)(aOb + (l15 + m * 16) * 448 + kt * 64 + quad * 16);
            #pragma unroll
            for (int n = 0; n < 2; ++n) {
                int NT = wv * 2 + n;
                bf16x8 bfr = *(const bf16x8*)(wf + WF_PROJ + ((NT * 6 + kt) * 64 + lane) * 8);
                #pragma unroll
                for (int m = 0; m < 3; ++m)
                    pacc[m][n] = __builtin_amdgcn_mfma_f32_16x16x32_bf16(af[m], bfr, pacc[m][n], 0, 0, 0);
            }
        }
        __syncthreads();   // all aO reads done before xw2 (and later aH2) writes
        #pragma unroll
        for (int n = 0; n < 2; ++n) {
            int c = (wv * 2 + n) * 16 + l15;
            float pb = proj_b[c];
            #pragma unroll
            for (int m = 0; m < 3; ++m)
                #pragma unroll
                for (int i = 0; i < 4; ++i) {
                    int r = m * 16 + q4 + i;
                    xw2[r * 196 + c] = x[sRowOff[r] + c] + pb + pacc[m][n][i];
                }
        }
    }
    __syncthreads();

    // ---- LN2 stats ----
    {
        int r = t >> 3, l = t & 7;
        const float* row = xw2 + r * 196;
        float s = 0.f, s2 = 0.f;
        for (int c = l; c < 192; c += 8) { float v = row[c]; s += v; s2 += v * v; }
        s += __shfl_xor(s, 1); s2 += __shfl_xor(s2, 1);
        s += __shfl_xor(s, 2); s2 += __shfl_xor(s2, 2);
        s += __shfl_xor(s, 4); s2 += __shfl_xor(s2, 4);
        if (l == 0) {
            float mu = s * (1.f / 192.f);
            float var = s2 * (1.f / 192.f) - mu * mu;
            sMu[r] = mu; sRs[r] = rsqrtf(var + 1e-5f);
        }
    }
    __syncthreads();
    for (int p = t; p < 4608; p += 384) {
        int r = p / 96, c2 = p % 96, c = c2 * 2;
        float mu = sMu[r], rs = sRs[r];
        float v0 = (xw2[r * 196 + c]     - mu) * rs * ln2_g[c]     + ln2_b[c];
        float v1 = (xw2[r * 196 + c + 1] - mu) * rs * ln2_g[c + 1] + ln2_b[c + 1];
        union { bf16_t h[2]; unsigned u; } pk;
        pk.h[0] = (bf16_t)v0; pk.h[1] = (bf16_t)v1;
        *(unsigned*)(aH2b + r * 448 + c2 * 4) = pk.u;
    }
    __syncthreads();

    // ================= MLP: 4 chunks of 192 hidden cols =================
    f32x4 acc2[3][2];
    #pragma unroll
    for (int m = 0; m < 3; ++m)
        #pragma unroll
        for (int n = 0; n < 2; ++n) {
            float b2 = mlp_b2[(wv * 2 + n) * 16 + l15];
            acc2[m][n] = (f32x4){b2, b2, b2, b2};
        }
    for (int ch = 0; ch < 4; ++ch) {
        f32x4 a1[3][2];
        #pragma unroll
        for (int m = 0; m < 3; ++m)
            #pragma unroll
            for (int n = 0; n < 2; ++n) {
                float b1 = mlp_b1[ch * 192 + (wv * 2 + n) * 16 + l15];
                a1[m][n] = (f32x4){b1, b1, b1, b1};
            }
        for (int kt = 0; kt < 6; ++kt) {
            bf16x8 af[3];
            #pragma unroll
            for (int m = 0; m < 3; ++m)
                af[m] = *(const bf16x8*)(aH2b + (l15 + m * 16) * 448 + kt * 64 + quad * 16);
            #pragma unroll
            for (int n = 0; n < 2; ++n) {
                int NT = ch * 12 + wv * 2 + n;
                bf16x8 bfr = *(const bf16x8*)(wf + WF_MLP1 + ((NT * 6 + kt) * 64 + lane) * 8);
                #pragma unroll
                for (int m = 0; m < 3; ++m)
                    a1[m][n] = __builtin_amdgcn_mfma_f32_16x16x32_bf16(af[m], bfr, a1[m][n], 0, 0, 0);
            }
        }
        // exact gelu -> aHid
        #pragma unroll
        for (int n = 0; n < 2; ++n) {
            int c = (wv * 2 + n) * 16 + l15;
            #pragma unroll
            for (int m = 0; m < 3; ++m)
                #pragma unroll
                for (int i = 0; i < 4; ++i) {
                    int r = m * 16 + q4 + i;
                    float v = a1[m][n][i];
                    float g = 0.5f * v * (1.f + erff(v * 0.70710678118654752f));
                    aHid[r * 224 + c] = (bf16_t)g;
                }
        }
        __syncthreads();
        // MLP2 partial over this K chunk
        for (int kt = 0; kt < 6; ++kt) {
            bf16x8 af[3];
            #pragma unroll
            for (int m = 0; m < 3; ++m)
                af[m] = *(const bf16x8*)(aHidb + (l15 + m * 16) * 448 + kt * 64 + quad * 16);
            #pragma unroll
            for (int n = 0; n < 2; ++n) {
                int NT = wv * 2 + n;
                int ktg = ch * 6 + kt;
                bf16x8 bfr = *(const bf16x8*)(wf + WF_MLP2 + ((NT * 24 + ktg) * 64 + lane) * 8);
                #pragma unroll
                for (int m = 0; m < 3; ++m)
                    acc2[m][n] = __builtin_amdgcn_mfma_f32_16x16x32_bf16(af[m], bfr, acc2[m][n], 0, 0, 0);
            }
        }
        __syncthreads();
    }

    // ---- final: out = xw2 + mlp ----
    #pragma unroll
    for (int n = 0; n < 2; ++n) {
        int c = (wv * 2 + n) * 16 + l15;
        #pragma unroll
        for (int m = 0; m < 3; ++m)
            #pragma unroll
            for (int i = 0; i < 4; ++i) {
                int r = m * 16 + q4 + i;
                out[sRowOff[r] + c] = xw2[r * 196 + c] + acc2[m][n][i];
            }
    }
}

extern "C" void kernel_launch(void* const* d_in, const int* in_sizes, int n_in,
                              void* d_out, int out_size, void* d_ws, size_t ws_size,
                              hipStream_t stream) {
    const float* x          = (const float*)d_in[0];
    const float* ln1_g      = (const float*)d_in[1];
    const float* ln1_b      = (const float*)d_in[2];
    const float* qkv_w      = (const float*)d_in[3];
    const float* qkv_b      = (const float*)d_in[4];
    const float* bias_table = (const float*)d_in[5];
    const float* proj_w     = (const float*)d_in[6];
    const float* proj_b     = (const float*)d_in[7];
    const float* ln2_g      = (const float*)d_in[8];
    const float* ln2_b      = (const float*)d_in[9];
    const float* mlp_w1     = (const float*)d_in[10];
    const float* mlp_b1     = (const float*)d_in[11];
    const float* mlp_w2     = (const float*)d_in[12];
    const float* mlp_b2     = (const float*)d_in[13];
    const int*   rel_index  = (const int*)d_in[14];
    float* out = (float*)d_out;
    bf16_t* wsb = (bf16_t*)d_ws;

    // weight pre-swizzle (runs every launch; d_ws is re-poisoned by harness)
    preproc_kernel<<<(55296 + 255) / 256, 256, 0, stream>>>(qkv_w, 576, 6, wsb + WF_QKV, 55296);
    preproc_kernel<<<(18432 + 255) / 256, 256, 0, stream>>>(proj_w, 192, 6, wsb + WF_PROJ, 18432);
    preproc_kernel<<<(73728 + 255) / 256, 256, 0, stream>>>(mlp_w1, 768, 6, wsb + WF_MLP1, 73728);
    preproc_kernel<<<(73728 + 255) / 256, 256, 0, stream>>>(mlp_w2, 192, 24, wsb + WF_MLP2, 73728);

    pangu_main<<<NBLK, 384, 0, stream>>>(
        x, ln1_g, ln1_b, qkv_b, bias_table, proj_b, ln2_g, ln2_b,
        mlp_b1, mlp_b2, rel_index, wsb, out);
}

// Round 4
// 665.703 us; speedup vs baseline: 3.5515x; 1.0209x over previous
//
#include <hip/hip_runtime.h>
#include <hip/hip_bf16.h>
#include <math.h>

typedef __bf16 bf16_t;
typedef __bf16 bf16x8 __attribute__((ext_vector_type(8)));
typedef float  f32x4  __attribute__((ext_vector_type(4)));

#define NBLK 2688          // 5376 windows / 2 per block
// pair offsets (1 pair = 2 bf16) of pre-swizzled weights inside d_ws
#define WP_QKV  0
#define WP_PROJ 55296
#define WP_MLP1 73728
#define WP_MLP2 147456
#define WP_TOT  221184
// bf16 element offsets
#define WF_QKV  0
#define WF_PROJ 110592
#define WF_MLP1 147456
#define WF_MLP2 294912

// ---------------- merged weight pre-swizzle: W[K][N] f32 -> B-fragment bf16 ----------------
// frag(nt,kt): dst[((nt*Kt + kt)*64 + lane)*8 + j] = W[kt*32 + (lane>>4)*8 + j][nt*16 + (lane&15)]
__global__ void preproc_all(const float* __restrict__ qkv_w, const float* __restrict__ proj_w,
                            const float* __restrict__ mlp_w1, const float* __restrict__ mlp_w2,
                            bf16_t* __restrict__ dst) {
    int p = blockIdx.x * 256 + threadIdx.x;
    if (p >= WP_TOT) return;
    const float* W; int N, Kt; int q = p;
    if (p < WP_PROJ)      { W = qkv_w;  N = 576; Kt = 6;  }
    else if (p < WP_MLP1) { W = proj_w; N = 192; Kt = 6;  q -= WP_PROJ; }
    else if (p < WP_MLP2) { W = mlp_w1; N = 768; Kt = 6;  q -= WP_MLP1; }
    else                  { W = mlp_w2; N = 192; Kt = 24; q -= WP_MLP2; }
    int j    = (q & 3) * 2;
    int lane = (q >> 2) & 63;
    int kt   = (q >> 8) % Kt;
    int nt   = (q >> 8) / Kt;
    int k = kt * 32 + (lane >> 4) * 8 + j;
    int n = nt * 16 + (lane & 15);
    union { bf16_t h[2]; unsigned u; } pk;
    pk.h[0] = (bf16_t)W[k * N + n];
    pk.h[1] = (bf16_t)W[(k + 1) * N + n];
    *(unsigned*)(dst + p * 2) = pk.u;
}

// ---------------- main fused kernel ----------------
// LDS arena (76032 B). bf16 activation rows: 192 cols in 400-B rows (200 elems).
// 400 B = 100 dw == 4 mod 32 -> b128 A-fragment reads stay bank-balanced.
//  aA   [0,25600)      bf16 [64][200]  LN1 out / QKV A (pad rows 24..31,56..63 garbage)
//  xtmp [25600,62464)  f32  [48][192]  phase 0 only (aliases wavebufs)
//  wavebufs 25600+wv*8320: Q[24][40] K[24][40] Vt[32][40] P[24][40] bf16
//  aO   [0,19200)      bf16 [48][200]  attn out / proj A  (aliases aA; barrier after QKV MFMA)
//  aH2  [0,19200)      bf16 [48][200]  LN2 out / MLP1 A   (aliases aO, dead)
//  aHid [19200,38400)  bf16 [48][200]  gelu chunk / MLP2 A
//  xw2  [38400,76032)  f32  [48][196]  residual1 (written after proj sync; wavebufs dead)
// Total with statics: 76608 B -> 2 blocks/CU (153216 <= 163840), 12 waves/CU.
__global__ __launch_bounds__(384, 3)
void pangu_main(const float* __restrict__ x,
                const float* __restrict__ ln1_g, const float* __restrict__ ln1_b,
                const float* __restrict__ qkv_b,
                const float* __restrict__ bias_table,
                const float* __restrict__ proj_b,
                const float* __restrict__ ln2_g, const float* __restrict__ ln2_b,
                const float* __restrict__ mlp_b1, const float* __restrict__ mlp_b2,
                const int* __restrict__ rel_index,
                const bf16_t* __restrict__ wf,
                float* __restrict__ out)
{
    __shared__ __align__(16) unsigned char arena[76032];
    __shared__ int   sRowOff[48];
    __shared__ float sMu[48], sRs[48];

    unsigned char* aAb   = arena;
    float*         xtmp  = (float*)(arena + 25600);
    unsigned char* aOb   = arena;                 // alias aA (post-QKV barrier)
    unsigned char* aH2b  = arena;                 // alias aO (dead)
    unsigned char* aHidb = arena + 19200;
    float*         xw2   = (float*)(arena + 38400);
    bf16_t* aO   = (bf16_t*)aOb;
    bf16_t* aHid = (bf16_t*)aHidb;

    const int t    = threadIdx.x;
    const int lane = t & 63;
    const int wv   = t >> 6;          // 0..5 (wave id == head id)
    const int quad = lane >> 4;
    const int l15  = lane & 15;
    const int q4   = quad * 4;

    // ---- row offsets of the 48 tokens (2 windows) ----
    if (t < 48) {
        int win = t / 24, tok = t % 24;
        int W = blockIdx.x * 2 + win;
        int id_ = W % 7;  int r1 = W / 7;
        int iw_ = r1 % 16; int r2 = r1 / 16;
        int ih_ = r2 % 24; int b  = r2 / 24;
        int i = tok / 12, j = (tok % 12) / 2, k = tok % 2;
        sRowOff[t] = (((b * 48 + ih_ * 2 + i) * 96 + iw_ * 6 + j) * 14 + id_ * 2 + k) * 192;
    }
    __syncthreads();

    // ---- phase 0: x -> xtmp (float4 coalesced) ----
    for (int q = t; q < 48 * 48; q += 384) {
        int r = q / 48, c4 = q % 48;
        *(float4*)(xtmp + r * 192 + c4 * 4) = *(const float4*)(x + sRowOff[r] + c4 * 4);
    }
    __syncthreads();

    // ---- LN1 stats: 8 lanes/row (384 = 48*8) ----
    {
        int r = t >> 3, l = t & 7;
        const float* row = xtmp + r * 192;
        float s = 0.f, s2 = 0.f;
        for (int c = l; c < 192; c += 8) { float v = row[c]; s += v; s2 += v * v; }
        s += __shfl_xor(s, 1); s2 += __shfl_xor(s2, 1);
        s += __shfl_xor(s, 2); s2 += __shfl_xor(s2, 2);
        s += __shfl_xor(s, 4); s2 += __shfl_xor(s2, 4);
        if (l == 0) {
            float mu = s * (1.f / 192.f);
            float var = s2 * (1.f / 192.f) - mu * mu;
            sMu[r] = mu; sRs[r] = rsqrtf(var + 1e-5f);
        }
    }
    __syncthreads();
    // ---- LN1 normalize -> aA (bf16 pairs, padded 64-row layout, 400-B rows) ----
    for (int p = t; p < 4608; p += 384) {
        int r48 = p / 96, c2 = p % 96, c = c2 * 2;
        int row = (r48 / 24) * 32 + (r48 % 24);
        float mu = sMu[r48], rs = sRs[r48];
        float v0 = (xtmp[r48 * 192 + c]     - mu) * rs * ln1_g[c]     + ln1_b[c];
        float v1 = (xtmp[r48 * 192 + c + 1] - mu) * rs * ln1_g[c + 1] + ln1_b[c + 1];
        union { bf16_t h[2]; unsigned u; } pk;
        pk.h[0] = (bf16_t)v0; pk.h[1] = (bf16_t)v1;
        *(unsigned*)(aAb + row * 400 + c2 * 4) = pk.u;
    }
    __syncthreads();

    // ================= QKV GEMM + attention =================
    {
        const int h = wv;
        unsigned char* wb = arena + 25600 + wv * 8320;
        bf16_t* Qb = (bf16_t*)wb;
        bf16_t* Kb = (bf16_t*)(wb + 1920);
        bf16_t* Vt = (bf16_t*)(wb + 3840);
        bf16_t* Pb = (bf16_t*)(wb + 6400);

        // QKV mini-GEMM: M tiles 0..3 (both windows), N = head's q/k/v (6 ntiles), K = 6 ktiles
        f32x4 acc[4][6];
        {
            float bq[6];
            const int ntg[6] = {2*h, 2*h+1, 12+2*h, 13+2*h, 24+2*h, 25+2*h};
            #pragma unroll
            for (int n = 0; n < 6; ++n) bq[n] = qkv_b[ntg[n] * 16 + l15];
            #pragma unroll
            for (int m = 0; m < 4; ++m)
                #pragma unroll
                for (int n = 0; n < 6; ++n)
                    acc[m][n] = (f32x4){bq[n], bq[n], bq[n], bq[n]};
            for (int kt = 0; kt < 6; ++kt) {
                bf16x8 af[4];
                #pragma unroll
                for (int m = 0; m < 4; ++m)
                    af[m] = *(const bf16x8*)(aAb + (l15 + m * 16) * 400 + kt * 64 + quad * 16);
                #pragma unroll
                for (int n = 0; n < 6; ++n) {
                    bf16x8 bfr = *(const bf16x8*)(wf + WF_QKV + ((ntg[n] * 6 + kt) * 64 + lane) * 8);
                    #pragma unroll
                    for (int m = 0; m < 4; ++m)
                        acc[m][n] = __builtin_amdgcn_mfma_f32_16x16x32_bf16(af[m], bfr, acc[m][n], 0, 0, 0);
                }
            }
        }
        __syncthreads();   // all waves done reading aA; aO (alias) may be written below

        // zero Vt pad tokens 24..31 (once; reused for both windows)
        {
            int c = lane >> 1, half = lane & 1;
            *(uint2*)((unsigned char*)Vt + c * 80 + 48 + half * 8) = make_uint2(0u, 0u);
        }

        const float scale = 0.1767766952966369f;  // 1/sqrt(32)
        #pragma unroll
        for (int win = 0; win < 2; ++win) {
            // scatter Q (scaled), K, V^T into wave-private bufs
            #pragma unroll
            for (int mt = 0; mt < 2; ++mt)
                #pragma unroll
                for (int i = 0; i < 4; ++i) {
                    int tok = mt * 16 + q4 + i;
                    if (tok < 24) {
                        #pragma unroll
                        for (int nt = 0; nt < 2; ++nt) {
                            int d = nt * 16 + l15;
                            Qb[tok * 40 + d]  = (bf16_t)(acc[2*win+mt][nt][i] * scale);
                            Kb[tok * 40 + d]  = (bf16_t)(acc[2*win+mt][2+nt][i]);
                            Vt[d * 40 + tok]  = (bf16_t)(acc[2*win+mt][4+nt][i]);
                        }
                    }
                }
            // S = Qs.K^T + bias  (bias gathered as C-init)
            f32x4 sacc[2][2];
            #pragma unroll
            for (int mt = 0; mt < 2; ++mt)
                #pragma unroll
                for (int nt = 0; nt < 2; ++nt)
                    #pragma unroll
                    for (int i = 0; i < 4; ++i) {
                        int n = mt * 16 + q4 + i; if (n > 23) n = 23;
                        int m = nt * 16 + l15;    if (m > 23) m = 23;
                        sacc[mt][nt][i] = bias_table[rel_index[n * 24 + m] * 6 + h];
                    }
            #pragma unroll
            for (int nt = 0; nt < 2; ++nt) {
                bf16x8 kf = *(const bf16x8*)((unsigned char*)Kb + (l15 + nt * 16) * 80 + quad * 16);
                #pragma unroll
                for (int mt = 0; mt < 2; ++mt) {
                    bf16x8 qf = *(const bf16x8*)((unsigned char*)Qb + (l15 + mt * 16) * 80 + quad * 16);
                    sacc[mt][nt] = __builtin_amdgcn_mfma_f32_16x16x32_bf16(qf, kf, sacc[mt][nt], 0, 0, 0);
                }
            }
            // in-register softmax over cols 0..23 (row lives in 16 lanes of one quad)
            #pragma unroll
            for (int mt = 0; mt < 2; ++mt)
                #pragma unroll
                for (int i = 0; i < 4; ++i) {
                    float s0 = sacc[mt][0][i];
                    float s1m = (l15 < 8) ? sacc[mt][1][i] : -1e30f;
                    float mx = fmaxf(s0, s1m);
                    mx = fmaxf(mx, __shfl_xor(mx, 1));
                    mx = fmaxf(mx, __shfl_xor(mx, 2));
                    mx = fmaxf(mx, __shfl_xor(mx, 4));
                    mx = fmaxf(mx, __shfl_xor(mx, 8));
                    float e0 = __expf(s0 - mx);
                    float e1 = (l15 < 8) ? __expf(sacc[mt][1][i] - mx) : 0.f;
                    float sum = e0 + e1;
                    sum += __shfl_xor(sum, 1);
                    sum += __shfl_xor(sum, 2);
                    sum += __shfl_xor(sum, 4);
                    sum += __shfl_xor(sum, 8);
                    float inv = 1.f / sum;
                    sacc[mt][0][i] = e0 * inv;
                    sacc[mt][1][i] = e1 * inv;   // 0 for cols 24..31
                }
            // P -> LDS (A-operand layout; cols 24..31 zeros)
            #pragma unroll
            for (int mt = 0; mt < 2; ++mt)
                #pragma unroll
                for (int i = 0; i < 4; ++i) {
                    int r = mt * 16 + q4 + i;
                    if (r < 24) {
                        Pb[r * 40 + l15]      = (bf16_t)sacc[mt][0][i];
                        Pb[r * 40 + 16 + l15] = (bf16_t)sacc[mt][1][i];
                    }
                }
            // O = P.V
            f32x4 oacc[2][2];
            #pragma unroll
            for (int mt = 0; mt < 2; ++mt)
                #pragma unroll
                for (int nt = 0; nt < 2; ++nt)
                    oacc[mt][nt] = (f32x4){0.f, 0.f, 0.f, 0.f};
            #pragma unroll
            for (int nt = 0; nt < 2; ++nt) {
                bf16x8 vf = *(const bf16x8*)((unsigned char*)Vt + (l15 + nt * 16) * 80 + quad * 16);
                #pragma unroll
                for (int mt = 0; mt < 2; ++mt) {
                    bf16x8 pf = *(const bf16x8*)((unsigned char*)Pb + (l15 + mt * 16) * 80 + quad * 16);
                    oacc[mt][nt] = __builtin_amdgcn_mfma_f32_16x16x32_bf16(pf, vf, oacc[mt][nt], 0, 0, 0);
                }
            }
            // O -> aO (48-row compact, proj A layout)
            #pragma unroll
            for (int mt = 0; mt < 2; ++mt)
                #pragma unroll
                for (int i = 0; i < 4; ++i) {
                    int tok = mt * 16 + q4 + i;
                    if (tok < 24) {
                        int r = win * 24 + tok;
                        #pragma unroll
                        for (int nt = 0; nt < 2; ++nt)
                            aO[r * 200 + h * 32 + nt * 16 + l15] = (bf16_t)oacc[mt][nt][i];
                    }
                }
        } // win
    }
    __syncthreads();

    // ================= proj GEMM (M=48, 2 ntiles/wave) + residual =================
    {
        f32x4 pacc[3][2];
        #pragma unroll
        for (int m = 0; m < 3; ++m)
            #pragma unroll
            for (int n = 0; n < 2; ++n) pacc[m][n] = (f32x4){0.f, 0.f, 0.f, 0.f};
        for (int kt = 0; kt < 6; ++kt) {
            bf16x8 af[3];
            #pragma unroll
            for (int m = 0; m < 3; ++m)
                af[m] = *(const bf16x8*)(aOb + (l15 + m * 16) * 400 + kt * 64 + quad * 16);
            #pragma unroll
            for (int n = 0; n < 2; ++n) {
                int NT = wv * 2 + n;
                bf16x8 bfr = *(const bf16x8*)(wf + WF_PROJ + ((NT * 6 + kt) * 64 + lane) * 8);
                #pragma unroll
                for (int m = 0; m < 3; ++m)
                    pacc[m][n] = __builtin_amdgcn_mfma_f32_16x16x32_bf16(af[m], bfr, pacc[m][n], 0, 0, 0);
            }
        }
        __syncthreads();   // all aO reads done before xw2 (and later aH2) writes
        #pragma unroll
        for (int n = 0; n < 2; ++n) {
            int c = (wv * 2 + n) * 16 + l15;
            float pb = proj_b[c];
            #pragma unroll
            for (int m = 0; m < 3; ++m)
                #pragma unroll
                for (int i = 0; i < 4; ++i) {
                    int r = m * 16 + q4 + i;
                    xw2[r * 196 + c] = x[sRowOff[r] + c] + pb + pacc[m][n][i];
                }
        }
    }
    __syncthreads();

    // ---- LN2 stats ----
    {
        int r = t >> 3, l = t & 7;
        const float* row = xw2 + r * 196;
        float s = 0.f, s2 = 0.f;
        for (int c = l; c < 192; c += 8) { float v = row[c]; s += v; s2 += v * v; }
        s += __shfl_xor(s, 1); s2 += __shfl_xor(s2, 1);
        s += __shfl_xor(s, 2); s2 += __shfl_xor(s2, 2);
        s += __shfl_xor(s, 4); s2 += __shfl_xor(s2, 4);
        if (l == 0) {
            float mu = s * (1.f / 192.f);
            float var = s2 * (1.f / 192.f) - mu * mu;
            sMu[r] = mu; sRs[r] = rsqrtf(var + 1e-5f);
        }
    }
    __syncthreads();
    for (int p = t; p < 4608; p += 384) {
        int r = p / 96, c2 = p % 96, c = c2 * 2;
        float mu = sMu[r], rs = sRs[r];
        float v0 = (xw2[r * 196 + c]     - mu) * rs * ln2_g[c]     + ln2_b[c];
        float v1 = (xw2[r * 196 + c + 1] - mu) * rs * ln2_g[c + 1] + ln2_b[c + 1];
        union { bf16_t h[2]; unsigned u; } pk;
        pk.h[0] = (bf16_t)v0; pk.h[1] = (bf16_t)v1;
        *(unsigned*)(aH2b + r * 400 + c2 * 4) = pk.u;
    }
    __syncthreads();

    // ================= MLP: 4 chunks of 192 hidden cols =================
    f32x4 acc2[3][2];
    #pragma unroll
    for (int m = 0; m < 3; ++m)
        #pragma unroll
        for (int n = 0; n < 2; ++n) {
            float b2 = mlp_b2[(wv * 2 + n) * 16 + l15];
            acc2[m][n] = (f32x4){b2, b2, b2, b2};
        }
    for (int ch = 0; ch < 4; ++ch) {
        f32x4 a1[3][2];
        #pragma unroll
        for (int m = 0; m < 3; ++m)
            #pragma unroll
            for (int n = 0; n < 2; ++n) {
                float b1 = mlp_b1[ch * 192 + (wv * 2 + n) * 16 + l15];
                a1[m][n] = (f32x4){b1, b1, b1, b1};
            }
        for (int kt = 0; kt < 6; ++kt) {
            bf16x8 af[3];
            #pragma unroll
            for (int m = 0; m < 3; ++m)
                af[m] = *(const bf16x8*)(aH2b + (l15 + m * 16) * 400 + kt * 64 + quad * 16);
            #pragma unroll
            for (int n = 0; n < 2; ++n) {
                int NT = ch * 12 + wv * 2 + n;
                bf16x8 bfr = *(const bf16x8*)(wf + WF_MLP1 + ((NT * 6 + kt) * 64 + lane) * 8);
                #pragma unroll
                for (int m = 0; m < 3; ++m)
                    a1[m][n] = __builtin_amdgcn_mfma_f32_16x16x32_bf16(af[m], bfr, a1[m][n], 0, 0, 0);
            }
        }
        // exact gelu -> aHid
        #pragma unroll
        for (int n = 0; n < 2; ++n) {
            int c = (wv * 2 + n) * 16 + l15;
            #pragma unroll
            for (int m = 0; m < 3; ++m)
                #pragma unroll
                for (int i = 0; i < 4; ++i) {
                    int r = m * 16 + q4 + i;
                    float v = a1[m][n][i];
                    float g = 0.5f * v * (1.f + erff(v * 0.70710678118654752f));
                    aHid[r * 200 + c] = (bf16_t)g;
                }
        }
        __syncthreads();
        // MLP2 partial over this K chunk
        for (int kt = 0; kt < 6; ++kt) {
            bf16x8 af[3];
            #pragma unroll
            for (int m = 0; m < 3; ++m)
                af[m] = *(const bf16x8*)(aHidb + (l15 + m * 16) * 400 + kt * 64 + quad * 16);
            #pragma unroll
            for (int n = 0; n < 2; ++n) {
                int NT = wv * 2 + n;
                int ktg = ch * 6 + kt;
                bf16x8 bfr = *(const bf16x8*)(wf + WF_MLP2 + ((NT * 24 + ktg) * 64 + lane) * 8);
                #pragma unroll
                for (int m = 0; m < 3; ++m)
                    acc2[m][n] = __builtin_amdgcn_mfma_f32_16x16x32_bf16(af[m], bfr, acc2[m][n], 0, 0, 0);
            }
        }
        __syncthreads();
    }

    // ---- final: out = xw2 + mlp ----
    #pragma unroll
    for (int n = 0; n < 2; ++n) {
        int c = (wv * 2 + n) * 16 + l15;
        #pragma unroll
        for (int m = 0; m < 3; ++m)
            #pragma unroll
            for (int i = 0; i < 4; ++i) {
                int r = m * 16 + q4 + i;
                out[sRowOff[r] + c] = xw2[r * 196 + c] + acc2[m][n][i];
            }
    }
}

extern "C" void kernel_launch(void* const* d_in, const int* in_sizes, int n_in,
                              void* d_out, int out_size, void* d_ws, size_t ws_size,
                              hipStream_t stream) {
    const float* x          = (const float*)d_in[0];
    const float* ln1_g      = (const float*)d_in[1];
    const float* ln1_b      = (const float*)d_in[2];
    const float* qkv_w      = (const float*)d_in[3];
    const float* qkv_b      = (const float*)d_in[4];
    const float* bias_table = (const float*)d_in[5];
    const float* proj_w     = (const float*)d_in[6];
    const float* proj_b     = (const float*)d_in[7];
    const float* ln2_g      = (const float*)d_in[8];
    const float* ln2_b      = (const float*)d_in[9];
    const float* mlp_w1     = (const float*)d_in[10];
    const float* mlp_b1     = (const float*)d_in[11];
    const float* mlp_w2     = (const float*)d_in[12];
    const float* mlp_b2     = (const float*)d_in[13];
    const int*   rel_index  = (const int*)d_in[14];
    float* out = (float*)d_out;
    bf16_t* wsb = (bf16_t*)d_ws;

    preproc_all<<<(WP_TOT + 255) / 256, 256, 0, stream>>>(qkv_w, proj_w, mlp_w1, mlp_w2, wsb);

    pangu_main<<<NBLK, 384, 0, stream>>>(
        x, ln1_g, ln1_b, qkv_b, bias_table, proj_b, ln2_g, ln2_b,
        mlp_b1, mlp_b2, rel_index, wsb, out);
}

// Round 5
// 641.463 us; speedup vs baseline: 3.6857x; 1.0378x over previous
//
#include <hip/hip_runtime.h>
#include <hip/hip_bf16.h>
#include <math.h>

typedef __bf16 bf16_t;
typedef __bf16 bf16x8 __attribute__((ext_vector_type(8)));
typedef float  f32x4  __attribute__((ext_vector_type(4)));

#define NBLK 2688          // 5376 windows / 2 per block
// pair offsets (1 pair = 2 bf16) of pre-swizzled weights inside d_ws
#define WP_QKV  0
#define WP_PROJ 55296
#define WP_MLP1 73728
#define WP_MLP2 147456
#define WP_TOT  221184
// bf16 element offsets
#define WF_QKV  0
#define WF_PROJ 110592
#define WF_MLP1 147456
#define WF_MLP2 294912

// ---------------- merged weight pre-swizzle: W[K][N] f32 -> B-fragment bf16 ----------------
// frag(nt,kt): dst[((nt*Kt + kt)*64 + lane)*8 + j] = W[kt*32 + (lane>>4)*8 + j][nt*16 + (lane&15)]
__global__ void preproc_all(const float* __restrict__ qkv_w, const float* __restrict__ proj_w,
                            const float* __restrict__ mlp_w1, const float* __restrict__ mlp_w2,
                            bf16_t* __restrict__ dst) {
    int p = blockIdx.x * 256 + threadIdx.x;
    if (p >= WP_TOT) return;
    const float* W; int N, Kt; int q = p;
    if (p < WP_PROJ)      { W = qkv_w;  N = 576; Kt = 6;  }
    else if (p < WP_MLP1) { W = proj_w; N = 192; Kt = 6;  q -= WP_PROJ; }
    else if (p < WP_MLP2) { W = mlp_w1; N = 768; Kt = 6;  q -= WP_MLP1; }
    else                  { W = mlp_w2; N = 192; Kt = 24; q -= WP_MLP2; }
    int j    = (q & 3) * 2;
    int lane = (q >> 2) & 63;
    int kt   = (q >> 8) % Kt;
    int nt   = (q >> 8) / Kt;
    int k = kt * 32 + (lane >> 4) * 8 + j;
    int n = nt * 16 + (lane & 15);
    union { bf16_t h[2]; unsigned u; } pk;
    pk.h[0] = (bf16_t)W[k * N + n];
    pk.h[1] = (bf16_t)W[(k + 1) * N + n];
    *(unsigned*)(dst + p * 2) = pk.u;
}

// ---------------- main fused kernel ----------------
// LDS arena (57600 B). bf16 activation rows: 192 cols in 400-B rows.
//  aA   [0,25600)      bf16 [64][200]  LN1 out / QKV A (pad rows 24..31,56..63 garbage)
//  wavebufs 25600+wv*4480 (4480 B/wave):
//      Qb [24][40] @0      (Pb aliases Qb; P pad-row reads spill into Kb/Vt = discarded rows)
//      Kb [24][40] @1920   (Vt [32][40] aliases Kb; V scattered AFTER S-MFMA reads K)
//  aO   [0,19200)      bf16 [48][200]  attn out / proj A (aliases aA; barrier after QKV MFMA)
//  aH2  [0,19200)      bf16 [48][200]  LN2 out / MLP1 A (aliases aO, dead)
//  xw2b [19200,38400)  bf16 [48][200]  residual1 copy (LN2 input only; f32 copy in regs)
//  aHid [38400,57600)  bf16 [48][200]  gelu chunk / MLP2 A
// Total with statics ~58176 B -> target 2 blocks/CU.
__global__ __launch_bounds__(384, 3)
void pangu_main(const float* __restrict__ x,
                const float* __restrict__ ln1_g, const float* __restrict__ ln1_b,
                const float* __restrict__ qkv_b,
                const float* __restrict__ bias_table,
                const float* __restrict__ proj_b,
                const float* __restrict__ ln2_g, const float* __restrict__ ln2_b,
                const float* __restrict__ mlp_b1, const float* __restrict__ mlp_b2,
                const int* __restrict__ rel_index,
                const bf16_t* __restrict__ wf,
                float* __restrict__ out)
{
    __shared__ __align__(16) unsigned char arena[57600];
    __shared__ int   sRowOff[48];
    __shared__ float sMu[48], sRs[48];

    unsigned char* aAb   = arena;
    unsigned char* aOb   = arena;                 // alias aA (post-QKV barrier)
    unsigned char* aH2b  = arena;                 // alias aO (dead)
    unsigned char* xw2b  = arena + 19200;
    unsigned char* aHidb = arena + 38400;
    bf16_t* aO   = (bf16_t*)aOb;
    bf16_t* aHid = (bf16_t*)aHidb;
    bf16_t* xw2h = (bf16_t*)xw2b;

    const int t    = threadIdx.x;
    const int lane = t & 63;
    const int wv   = t >> 6;          // 0..5 (wave id == head id)
    const int quad = lane >> 4;
    const int l15  = lane & 15;
    const int q4   = quad * 4;

    // ---- row offsets of the 48 tokens (2 windows) ----
    if (t < 48) {
        int win = t / 24, tok = t % 24;
        int W = blockIdx.x * 2 + win;
        int id_ = W % 7;  int r1 = W / 7;
        int iw_ = r1 % 16; int r2 = r1 / 16;
        int ih_ = r2 % 24; int b  = r2 / 24;
        int i = tok / 12, j = (tok % 12) / 2, k = tok % 2;
        sRowOff[t] = (((b * 48 + ih_ * 2 + i) * 96 + iw_ * 6 + j) * 14 + id_ * 2 + k) * 192;
    }
    __syncthreads();

    // ---- LN1 entirely in registers: 8 threads/row, 24 f32 each ----
    {
        int r48 = t >> 3, l = t & 7;
        const float* xr = x + sRowOff[r48];
        float4 v[6];
        #pragma unroll
        for (int s = 0; s < 6; ++s) v[s] = *(const float4*)(xr + l * 4 + s * 32);
        float sm = 0.f, s2 = 0.f;
        #pragma unroll
        for (int s = 0; s < 6; ++s) {
            sm += v[s].x + v[s].y + v[s].z + v[s].w;
            s2 += v[s].x * v[s].x + v[s].y * v[s].y + v[s].z * v[s].z + v[s].w * v[s].w;
        }
        sm += __shfl_xor(sm, 1); s2 += __shfl_xor(s2, 1);
        sm += __shfl_xor(sm, 2); s2 += __shfl_xor(s2, 2);
        sm += __shfl_xor(sm, 4); s2 += __shfl_xor(s2, 4);
        float mu = sm * (1.f / 192.f);
        float var = s2 * (1.f / 192.f) - mu * mu;
        float rs = rsqrtf(var + 1e-5f);
        int row = (r48 / 24) * 32 + (r48 % 24);
        #pragma unroll
        for (int s = 0; s < 6; ++s) {
            int c = l * 4 + s * 32;
            union { bf16_t h[4]; uint2 u; } pk;
            pk.h[0] = (bf16_t)((v[s].x - mu) * rs * ln1_g[c]     + ln1_b[c]);
            pk.h[1] = (bf16_t)((v[s].y - mu) * rs * ln1_g[c + 1] + ln1_b[c + 1]);
            pk.h[2] = (bf16_t)((v[s].z - mu) * rs * ln1_g[c + 2] + ln1_b[c + 2]);
            pk.h[3] = (bf16_t)((v[s].w - mu) * rs * ln1_g[c + 3] + ln1_b[c + 3]);
            *(uint2*)(aAb + row * 400 + c * 2) = pk.u;
        }
    }
    __syncthreads();

    // ================= QKV GEMM + attention =================
    {
        const int h = wv;
        unsigned char* wb = arena + 25600 + wv * 4480;
        bf16_t* Qb = (bf16_t*)wb;                 // Pb aliases Qb
        bf16_t* Kb = (bf16_t*)(wb + 1920);        // Vt aliases Kb
        bf16_t* Vt = (bf16_t*)(wb + 1920);
        bf16_t* Pb = (bf16_t*)wb;

        // QKV mini-GEMM: M tiles 0..3 (both windows), N = head's q/k/v (6 ntiles), K = 6 ktiles
        f32x4 acc[4][6];
        {
            float bq[6];
            const int ntg[6] = {2*h, 2*h+1, 12+2*h, 13+2*h, 24+2*h, 25+2*h};
            #pragma unroll
            for (int n = 0; n < 6; ++n) bq[n] = qkv_b[ntg[n] * 16 + l15];
            #pragma unroll
            for (int m = 0; m < 4; ++m)
                #pragma unroll
                for (int n = 0; n < 6; ++n)
                    acc[m][n] = (f32x4){bq[n], bq[n], bq[n], bq[n]};
            for (int kt = 0; kt < 6; ++kt) {
                bf16x8 af[4];
                #pragma unroll
                for (int m = 0; m < 4; ++m)
                    af[m] = *(const bf16x8*)(aAb + (l15 + m * 16) * 400 + kt * 64 + quad * 16);
                #pragma unroll
                for (int n = 0; n < 6; ++n) {
                    bf16x8 bfr = *(const bf16x8*)(wf + WF_QKV + ((ntg[n] * 6 + kt) * 64 + lane) * 8);
                    #pragma unroll
                    for (int m = 0; m < 4; ++m)
                        acc[m][n] = __builtin_amdgcn_mfma_f32_16x16x32_bf16(af[m], bfr, acc[m][n], 0, 0, 0);
                }
            }
        }
        __syncthreads();   // all waves done reading aA; aO (alias) written below

        const float scale = 0.1767766952966369f;  // 1/sqrt(32)
        #pragma unroll
        for (int win = 0; win < 2; ++win) {
            // scatter Q (scaled) and K only (V deferred; Vt aliases Kb)
            #pragma unroll
            for (int mt = 0; mt < 2; ++mt)
                #pragma unroll
                for (int i = 0; i < 4; ++i) {
                    int tok = mt * 16 + q4 + i;
                    if (tok < 24) {
                        #pragma unroll
                        for (int nt = 0; nt < 2; ++nt) {
                            int d = nt * 16 + l15;
                            Qb[tok * 40 + d] = (bf16_t)(acc[2*win+mt][nt][i] * scale);
                            Kb[tok * 40 + d] = (bf16_t)(acc[2*win+mt][2+nt][i]);
                        }
                    }
                }
            // S = Qs.K^T + bias  (bias gathered as C-init)
            f32x4 sacc[2][2];
            #pragma unroll
            for (int mt = 0; mt < 2; ++mt)
                #pragma unroll
                for (int nt = 0; nt < 2; ++nt)
                    #pragma unroll
                    for (int i = 0; i < 4; ++i) {
                        int n = mt * 16 + q4 + i; if (n > 23) n = 23;
                        int m = nt * 16 + l15;    if (m > 23) m = 23;
                        sacc[mt][nt][i] = bias_table[rel_index[n * 24 + m] * 6 + h];
                    }
            #pragma unroll
            for (int nt = 0; nt < 2; ++nt) {
                bf16x8 kf = *(const bf16x8*)((unsigned char*)Kb + (l15 + nt * 16) * 80 + quad * 16);
                #pragma unroll
                for (int mt = 0; mt < 2; ++mt) {
                    bf16x8 qf = *(const bf16x8*)((unsigned char*)Qb + (l15 + mt * 16) * 80 + quad * 16);
                    sacc[mt][nt] = __builtin_amdgcn_mfma_f32_16x16x32_bf16(qf, kf, sacc[mt][nt], 0, 0, 0);
                }
            }
            // V scatter now (Kb dead): real toks + zero pads 24..31
            #pragma unroll
            for (int mt = 0; mt < 2; ++mt)
                #pragma unroll
                for (int i = 0; i < 4; ++i) {
                    int tok = mt * 16 + q4 + i;
                    if (tok < 24) {
                        #pragma unroll
                        for (int nt = 0; nt < 2; ++nt)
                            Vt[(nt * 16 + l15) * 40 + tok] = (bf16_t)(acc[2*win+mt][4+nt][i]);
                    }
                }
            {
                int d = lane >> 1, half = lane & 1;
                *(uint2*)((unsigned char*)Vt + d * 80 + 48 + half * 8) = make_uint2(0u, 0u);
            }
            // in-register softmax over cols 0..23 (row lives in 16 lanes of one quad)
            #pragma unroll
            for (int mt = 0; mt < 2; ++mt)
                #pragma unroll
                for (int i = 0; i < 4; ++i) {
                    float s0 = sacc[mt][0][i];
                    float s1m = (l15 < 8) ? sacc[mt][1][i] : -1e30f;
                    float mx = fmaxf(s0, s1m);
                    mx = fmaxf(mx, __shfl_xor(mx, 1));
                    mx = fmaxf(mx, __shfl_xor(mx, 2));
                    mx = fmaxf(mx, __shfl_xor(mx, 4));
                    mx = fmaxf(mx, __shfl_xor(mx, 8));
                    float e0 = __expf(s0 - mx);
                    float e1 = (l15 < 8) ? __expf(sacc[mt][1][i] - mx) : 0.f;
                    float sum = e0 + e1;
                    sum += __shfl_xor(sum, 1);
                    sum += __shfl_xor(sum, 2);
                    sum += __shfl_xor(sum, 4);
                    sum += __shfl_xor(sum, 8);
                    float inv = 1.f / sum;
                    sacc[mt][0][i] = e0 * inv;
                    sacc[mt][1][i] = e1 * inv;   // 0 for cols 24..31
                }
            // P -> LDS (A-operand layout; aliases Qb, Q dead)
            #pragma unroll
            for (int mt = 0; mt < 2; ++mt)
                #pragma unroll
                for (int i = 0; i < 4; ++i) {
                    int r = mt * 16 + q4 + i;
                    if (r < 24) {
                        Pb[r * 40 + l15]      = (bf16_t)sacc[mt][0][i];
                        Pb[r * 40 + 16 + l15] = (bf16_t)sacc[mt][1][i];
                    }
                }
            // O = P.V
            f32x4 oacc[2][2];
            #pragma unroll
            for (int mt = 0; mt < 2; ++mt)
                #pragma unroll
                for (int nt = 0; nt < 2; ++nt)
                    oacc[mt][nt] = (f32x4){0.f, 0.f, 0.f, 0.f};
            #pragma unroll
            for (int nt = 0; nt < 2; ++nt) {
                bf16x8 vf = *(const bf16x8*)((unsigned char*)Vt + (l15 + nt * 16) * 80 + quad * 16);
                #pragma unroll
                for (int mt = 0; mt < 2; ++mt) {
                    bf16x8 pf = *(const bf16x8*)((unsigned char*)Pb + (l15 + mt * 16) * 80 + quad * 16);
                    oacc[mt][nt] = __builtin_amdgcn_mfma_f32_16x16x32_bf16(pf, vf, oacc[mt][nt], 0, 0, 0);
                }
            }
            // O -> aO (48-row compact, proj A layout)
            #pragma unroll
            for (int mt = 0; mt < 2; ++mt)
                #pragma unroll
                for (int i = 0; i < 4; ++i) {
                    int tok = mt * 16 + q4 + i;
                    if (tok < 24) {
                        int r = win * 24 + tok;
                        #pragma unroll
                        for (int nt = 0; nt < 2; ++nt)
                            aO[r * 200 + h * 32 + nt * 16 + l15] = (bf16_t)oacc[mt][nt][i];
                    }
                }
        } // win
    }
    __syncthreads();

    // ================= proj GEMM (M=48, 2 ntiles/wave) + residual =================
    float rxw[3][2][4];   // f32 residual carried in registers to the final store
    {
        f32x4 pacc[3][2];
        #pragma unroll
        for (int m = 0; m < 3; ++m)
            #pragma unroll
            for (int n = 0; n < 2; ++n) pacc[m][n] = (f32x4){0.f, 0.f, 0.f, 0.f};
        for (int kt = 0; kt < 6; ++kt) {
            bf16x8 af[3];
            #pragma unroll
            for (int m = 0; m < 3; ++m)
                af[m] = *(const bf16x8*)(aOb + (l15 + m * 16) * 400 + kt * 64 + quad * 16);
            #pragma unroll
            for (int n = 0; n < 2; ++n) {
                int NT = wv * 2 + n;
                bf16x8 bfr = *(const bf16x8*)(wf + WF_PROJ + ((NT * 6 + kt) * 64 + lane) * 8);
                #pragma unroll
                for (int m = 0; m < 3; ++m)
                    pacc[m][n] = __builtin_amdgcn_mfma_f32_16x16x32_bf16(af[m], bfr, pacc[m][n], 0, 0, 0);
            }
        }
        __syncthreads();   // all aO reads done before xw2b/aH2 writes
        #pragma unroll
        for (int n = 0; n < 2; ++n) {
            int c = (wv * 2 + n) * 16 + l15;
            float pb = proj_b[c];
            #pragma unroll
            for (int m = 0; m < 3; ++m)
                #pragma unroll
                for (int i = 0; i < 4; ++i) {
                    int r = m * 16 + q4 + i;
                    float val = x[sRowOff[r] + c] + pb + pacc[m][n][i];
                    rxw[m][n][i] = val;
                    xw2h[r * 200 + c] = (bf16_t)val;
                }
        }
    }
    __syncthreads();

    // ---- LN2 stats from bf16 xw2 copy ----
    {
        int r = t >> 3, l = t & 7;
        float sm = 0.f, s2 = 0.f;
        #pragma unroll
        for (int s = 0; s < 6; ++s) {
            union { bf16_t h[4]; uint2 u; } pk;
            pk.u = *(const uint2*)(xw2b + r * 400 + l * 8 + s * 64);
            #pragma unroll
            for (int z = 0; z < 4; ++z) { float v = (float)pk.h[z]; sm += v; s2 += v * v; }
        }
        sm += __shfl_xor(sm, 1); s2 += __shfl_xor(s2, 1);
        sm += __shfl_xor(sm, 2); s2 += __shfl_xor(s2, 2);
        sm += __shfl_xor(sm, 4); s2 += __shfl_xor(s2, 4);
        if (l == 0) {
            float mu = sm * (1.f / 192.f);
            float var = s2 * (1.f / 192.f) - mu * mu;
            sMu[r] = mu; sRs[r] = rsqrtf(var + 1e-5f);
        }
    }
    __syncthreads();
    // ---- LN2 normalize -> aH2 ----
    for (int p = t; p < 4608; p += 384) {
        int r = p / 96, c2 = p % 96, c = c2 * 2;
        float mu = sMu[r], rs = sRs[r];
        union { bf16_t h[2]; unsigned u; } in, pk;
        in.u = *(const unsigned*)(xw2b + r * 400 + c2 * 4);
        pk.h[0] = (bf16_t)(((float)in.h[0] - mu) * rs * ln2_g[c]     + ln2_b[c]);
        pk.h[1] = (bf16_t)(((float)in.h[1] - mu) * rs * ln2_g[c + 1] + ln2_b[c + 1]);
        *(unsigned*)(aH2b + r * 400 + c2 * 4) = pk.u;
    }
    __syncthreads();

    // ================= MLP: 4 chunks of 192 hidden cols =================
    f32x4 acc2[3][2];
    #pragma unroll
    for (int m = 0; m < 3; ++m)
        #pragma unroll
        for (int n = 0; n < 2; ++n) {
            float b2 = mlp_b2[(wv * 2 + n) * 16 + l15];
            acc2[m][n] = (f32x4){b2, b2, b2, b2};
        }
    for (int ch = 0; ch < 4; ++ch) {
        f32x4 a1[3][2];
        #pragma unroll
        for (int m = 0; m < 3; ++m)
            #pragma unroll
            for (int n = 0; n < 2; ++n) {
                float b1 = mlp_b1[ch * 192 + (wv * 2 + n) * 16 + l15];
                a1[m][n] = (f32x4){b1, b1, b1, b1};
            }
        for (int kt = 0; kt < 6; ++kt) {
            bf16x8 af[3];
            #pragma unroll
            for (int m = 0; m < 3; ++m)
                af[m] = *(const bf16x8*)(aH2b + (l15 + m * 16) * 400 + kt * 64 + quad * 16);
            #pragma unroll
            for (int n = 0; n < 2; ++n) {
                int NT = ch * 12 + wv * 2 + n;
                bf16x8 bfr = *(const bf16x8*)(wf + WF_MLP1 + ((NT * 6 + kt) * 64 + lane) * 8);
                #pragma unroll
                for (int m = 0; m < 3; ++m)
                    a1[m][n] = __builtin_amdgcn_mfma_f32_16x16x32_bf16(af[m], bfr, a1[m][n], 0, 0, 0);
            }
        }
        // exact gelu -> aHid
        #pragma unroll
        for (int n = 0; n < 2; ++n) {
            int c = (wv * 2 + n) * 16 + l15;
            #pragma unroll
            for (int m = 0; m < 3; ++m)
                #pragma unroll
                for (int i = 0; i < 4; ++i) {
                    int r = m * 16 + q4 + i;
                    float v = a1[m][n][i];
                    float g = 0.5f * v * (1.f + erff(v * 0.70710678118654752f));
                    aHid[r * 200 + c] = (bf16_t)g;
                }
        }
        __syncthreads();
        // MLP2 partial over this K chunk
        for (int kt = 0; kt < 6; ++kt) {
            bf16x8 af[3];
            #pragma unroll
            for (int m = 0; m < 3; ++m)
                af[m] = *(const bf16x8*)(aHidb + (l15 + m * 16) * 400 + kt * 64 + quad * 16);
            #pragma unroll
            for (int n = 0; n < 2; ++n) {
                int NT = wv * 2 + n;
                int ktg = ch * 6 + kt;
                bf16x8 bfr = *(const bf16x8*)(wf + WF_MLP2 + ((NT * 24 + ktg) * 64 + lane) * 8);
                #pragma unroll
                for (int m = 0; m < 3; ++m)
                    acc2[m][n] = __builtin_amdgcn_mfma_f32_16x16x32_bf16(af[m], bfr, acc2[m][n], 0, 0, 0);
            }
        }
        __syncthreads();
    }

    // ---- final: out = xw2(regs) + mlp ----
    #pragma unroll
    for (int n = 0; n < 2; ++n) {
        int c = (wv * 2 + n) * 16 + l15;
        #pragma unroll
        for (int m = 0; m < 3; ++m)
            #pragma unroll
            for (int i = 0; i < 4; ++i) {
                int r = m * 16 + q4 + i;
                out[sRowOff[r] + c] = rxw[m][n][i] + acc2[m][n][i];
            }
    }
}

extern "C" void kernel_launch(void* const* d_in, const int* in_sizes, int n_in,
                              void* d_out, int out_size, void* d_ws, size_t ws_size,
                              hipStream_t stream) {
    const float* x          = (const float*)d_in[0];
    const float* ln1_g      = (const float*)d_in[1];
    const float* ln1_b      = (const float*)d_in[2];
    const float* qkv_w      = (const float*)d_in[3];
    const float* qkv_b      = (const float*)d_in[4];
    const float* bias_table = (const float*)d_in[5];
    const float* proj_w     = (const float*)d_in[6];
    const float* proj_b     = (const float*)d_in[7];
    const float* ln2_g      = (const float*)d_in[8];
    const float* ln2_b      = (const float*)d_in[9];
    const float* mlp_w1     = (const float*)d_in[10];
    const float* mlp_b1     = (const float*)d_in[11];
    const float* mlp_w2     = (const float*)d_in[12];
    const float* mlp_b2     = (const float*)d_in[13];
    const int*   rel_index  = (const int*)d_in[14];
    float* out = (float*)d_out;
    bf16_t* wsb = (bf16_t*)d_ws;

    preproc_all<<<(WP_TOT + 255) / 256, 256, 0, stream>>>(qkv_w, proj_w, mlp_w1, mlp_w2, wsb);

    pangu_main<<<NBLK, 384, 0, stream>>>(
        x, ln1_g, ln1_b, qkv_b, bias_table, proj_b, ln2_g, ln2_b,
        mlp_b1, mlp_b2, rel_index, wsb, out);
}